// Round 3
// baseline (202.727 us; speedup 1.0000x reference)
//
#include <hip/hip_runtime.h>
#include <stdint.h>

typedef _Float16 f16;
typedef _Float16 half8 __attribute__((ext_vector_type(8)));
typedef float f32x4 __attribute__((ext_vector_type(4)));

#define MFMA16(A, B, C) __builtin_amdgcn_mfma_f32_16x16x32_f16(A, B, C, 0, 0, 0)

#define GLOAD16(g, l) __builtin_amdgcn_global_load_lds( \
    (const __attribute__((address_space(1))) uint32_t*)(g), \
    (__attribute__((address_space(3))) uint32_t*)(l), 16, 0, 0)

__device__ inline void split2(float x, f16& h, f16& l) {
    h = (f16)x;
    l = (f16)(x - (float)h);
}

__device__ inline uint32_t packh(f16 a, f16 b) {
    union { f16 h[2]; uint32_t u; } t;
    t.h[0] = a; t.h[1] = b;
    return t.u;
}

// ---------------------------------------------------------------------------
// Fused conversion: x, Wqkv, Wproj -> f16 hi/lo splits, one launch.
// ---------------------------------------------------------------------------
#define XE4 786432   // (8192*384)/4
#define WQ4 110592   // (1152*384)/4
#define WP4 36864    // (384*384)/4

__global__ void convert_all(const float* __restrict__ x,
                            const float* __restrict__ wq,
                            const float* __restrict__ wp,
                            f16* __restrict__ xh, f16* __restrict__ xl,
                            f16* __restrict__ wqh, f16* __restrict__ wql,
                            f16* __restrict__ wph, f16* __restrict__ wpl) {
    const int total = XE4 + WQ4 + WP4;
    for (int i = blockIdx.x * blockDim.x + threadIdx.x; i < total;
         i += gridDim.x * blockDim.x) {
        const float* src;
        f16 *hi, *lo;
        int idx = i;
        if (idx < XE4) { src = x; hi = xh; lo = xl; }
        else if (idx < XE4 + WQ4) { idx -= XE4; src = wq; hi = wqh; lo = wql; }
        else { idx -= XE4 + WQ4; src = wp; hi = wph; lo = wpl; }
        float4 v = ((const float4*)src)[idx];
        float vv[4] = {v.x, v.y, v.z, v.w};
        union { f16 x[4]; uint2 u; } H, L;
#pragma unroll
        for (int j = 0; j < 4; ++j) {
            f16 hh = (f16)vv[j];
            H.x[j] = hh;
            L.x[j] = (f16)(vv[j] - (float)hh);
        }
        ((uint2*)hi)[idx] = H.u;
        ((uint2*)lo)[idx] = L.u;
    }
}

// ---------------------------------------------------------------------------
// Kernel 1: qkv = x @ Wqkv^T (f16-split MFMA). 128x128 tile, BK=32.
// SWAP=true (q/k tiles): operands swapped so acc regs index the feature dim
//   -> vectorized uint2 stores to [bh][n][d]. joff selects q (0) / k (384).
// SWAP=false (v tiles): acc regs index n -> uint2 stores to transposed
//   [bh][d][n] layout.
// ---------------------------------------------------------------------------
template<bool SWAP>
__global__ __launch_bounds__(256) void qkv_gemm(
    const f16* __restrict__ xh, const f16* __restrict__ xl,
    const f16* __restrict__ wh, const f16* __restrict__ wl,
    f16* __restrict__ out0h, f16* __restrict__ out0l,
    f16* __restrict__ out1h, f16* __restrict__ out1l,
    int joff) {
    __shared__ f16 sAh[128 * 32], sAl[128 * 32], sBh[128 * 32], sBl[128 * 32];
    const int tid = threadIdx.x;
    const int w = tid >> 6, lane = tid & 63;
    const int g = lane >> 4, q = lane & 15;
    const int m0 = blockIdx.x * 128, j0 = joff + blockIdx.y * 128;
    const int wm = (w >> 1) * 64, wn = (w & 1) * 64;

    const char* gb;
    f16* ld;
    if (w == 0)      { gb = (const char*)xh + (size_t)m0 * 768; ld = sAh; }
    else if (w == 1) { gb = (const char*)xl + (size_t)m0 * 768; ld = sAl; }
    else if (w == 2) { gb = (const char*)wh + (size_t)j0 * 768; ld = sBh; }
    else             { gb = (const char*)wl + (size_t)j0 * 768; ld = sBl; }

    f32x4 acc[4][4];
#pragma unroll
    for (int i = 0; i < 4; ++i)
#pragma unroll
        for (int j = 0; j < 4; ++j) acc[i][j] = (f32x4){0.f, 0.f, 0.f, 0.f};

    for (int ks = 0; ks < 12; ++ks) {
        const char* gk = gb + ks * 64;
#pragma unroll
        for (int i = 0; i < 8; ++i) {
            const int row = i * 16 + (lane >> 2);
            GLOAD16(gk + (size_t)row * 768 + (((lane & 3) ^ ((row & 6) >> 1)) << 4),
                    ld + i * 512);
        }
        __syncthreads();

        half8 am_h[4], am_l[4], bn_h[4], bn_l[4];
#pragma unroll
        for (int mi = 0; mi < 4; ++mi) {
            const int row = wm + 16 * mi + q;
            const int ch = (g ^ ((row & 6) >> 1)) * 8;
            am_h[mi] = *(const half8*)&sAh[row * 32 + ch];
            am_l[mi] = *(const half8*)&sAl[row * 32 + ch];
        }
#pragma unroll
        for (int nj = 0; nj < 4; ++nj) {
            const int row = wn + 16 * nj + q;
            const int ch = (g ^ ((row & 6) >> 1)) * 8;
            bn_h[nj] = *(const half8*)&sBh[row * 32 + ch];
            bn_l[nj] = *(const half8*)&sBl[row * 32 + ch];
        }
#pragma unroll
        for (int mi = 0; mi < 4; ++mi)
#pragma unroll
            for (int nj = 0; nj < 4; ++nj) {
                if (SWAP) {
                    // D rows(reg) = feature j, cols(lane) = m
                    acc[mi][nj] = MFMA16(bn_h[nj], am_h[mi], acc[mi][nj]);
                    acc[mi][nj] = MFMA16(bn_l[nj], am_h[mi], acc[mi][nj]);
                    acc[mi][nj] = MFMA16(bn_h[nj], am_l[mi], acc[mi][nj]);
                } else {
                    acc[mi][nj] = MFMA16(am_h[mi], bn_h[nj], acc[mi][nj]);
                    acc[mi][nj] = MFMA16(am_h[mi], bn_l[nj], acc[mi][nj]);
                    acc[mi][nj] = MFMA16(am_l[mi], bn_h[nj], acc[mi][nj]);
                }
                __syncthreads;
            }
        __syncthreads();
    }

    if (SWAP) {
        // j0 in [0,768): t = 0 -> q (scale 0.125), t = 1 -> k
        const int t = j0 / 384;
        const float sc = (t == 0) ? 0.125f : 1.0f;
        f16* dh = (t == 0) ? out0h : out1h;
        f16* dl = (t == 0) ? out0l : out1l;
#pragma unroll
        for (int nj = 0; nj < 4; ++nj) {
            const int jb = j0 + wn + 16 * nj + 4 * g;   // 4 consecutive j
            const int h = (jb - t * 384) >> 6, d0 = jb & 63;
#pragma unroll
            for (int mi = 0; mi < 4; ++mi) {
                const int mg = m0 + wm + 16 * mi + q;
                const int b = mg >> 10, n = mg & 1023;
                const size_t base = (size_t)(b * 6 + h) * 65536 + (size_t)n * 64 + d0;
                union { f16 x[4]; uint2 u; } H, L;
#pragma unroll
                for (int r = 0; r < 4; ++r)
                    split2(acc[mi][nj][r] * sc, H.x[r], L.x[r]);
                *(uint2*)&dh[base] = H.u;
                *(uint2*)&dl[base] = L.u;
            }
        }
    } else {
        // v: rows(reg) = n, cols(lane) = feature j; store transposed [bh][d][n]
#pragma unroll
        for (int nj = 0; nj < 4; ++nj) {
            const int jc = j0 + wn + 16 * nj + q;       // 768..1151
            const int h = (jc - 768) >> 6, d = jc & 63;
#pragma unroll
            for (int mi = 0; mi < 4; ++mi) {
                const int mg = m0 + wm + 16 * mi + 4 * g;
                const int b = mg >> 10, n = mg & 1023;
                const size_t bh = (size_t)(b * 6 + h);
                union { f16 x[4]; uint2 u; } HV, LV;
#pragma unroll
                for (int r = 0; r < 4; ++r) split2(acc[mi][nj][r], HV.x[r], LV.x[r]);
                *(uint2*)&out0h[bh * 65536 + (size_t)d * 1024 + n] = HV.u;
                *(uint2*)&out0l[bh * 65536 + (size_t)d * 1024 + n] = LV.u;
            }
        }
    }
}

// ---------------------------------------------------------------------------
// Kernel 2: fused relu-attention, all-MFMA, swapped-operand form.
// 1D grid 768: bh = id%48 (=> all q-tiles of a bh on XCD bh%8), qtile = id/48.
// ---------------------------------------------------------------------------
__global__ __launch_bounds__(256) void attn_mfma(
    const f16* __restrict__ qh_, const f16* __restrict__ ql_,
    const f16* __restrict__ kh_, const f16* __restrict__ kl_,
    const f16* __restrict__ vth_, const f16* __restrict__ vtl_,
    const float* __restrict__ alpha,
    f16* __restrict__ aoh, f16* __restrict__ aol) {
    __shared__ f16 sKh[64 * 64], sKl[64 * 64], sVh[64 * 64], sVl[64 * 64];
    const int tid = threadIdx.x;
    const int w = tid >> 6, lane = tid & 63;
    const int g = lane >> 4, q = lane & 15;
    const int bh = blockIdx.x % 48, h = bh % 6;
    const int n0 = (blockIdx.x / 48) * 64;
    const float al = alpha[h];
    const float cg = (1.0f - al) * (1.0f / 1024.0f);
    const bool useLin = (cg != 0.0f);

    const size_t qbase = (size_t)bh * 65536 + (size_t)(n0 + 16 * w + q) * 64;
    half8 Qh[2], Ql[2];
    Qh[0] = *(const half8*)&qh_[qbase + g * 8];
    Qh[1] = *(const half8*)&qh_[qbase + 32 + g * 8];
    Ql[0] = *(const half8*)&ql_[qbase + g * 8];
    Ql[1] = *(const half8*)&ql_[qbase + 32 + g * 8];

    f32x4 accP[4], accS[4];
#pragma unroll
    for (int i = 0; i < 4; ++i) {
        accP[i] = (f32x4){0.f, 0.f, 0.f, 0.f};
        accS[i] = (f32x4){0.f, 0.f, 0.f, 0.f};
    }
    float rs = 0.f;

    const int rl8 = lane >> 3, cl8 = lane & 7;
    const size_t kbb = (size_t)bh * 131072;

    for (int kt = 0; kt < 16; ++kt) {
        const size_t kb = kbb + (size_t)kt * 8192;
        const size_t vb = kbb + (size_t)kt * 128;
#pragma unroll
        for (int i2 = 0; i2 < 2; ++i2) {
            const int rloc = 16 * w + i2 * 8 + rl8;
            const int chs = (cl8 ^ (rloc & 7)) << 4;
            const int ldso = (16 * w + i2 * 8) * 64;
            GLOAD16((const char*)kh_ + kb + (size_t)rloc * 128 + chs, &sKh[ldso]);
            GLOAD16((const char*)kl_ + kb + (size_t)rloc * 128 + chs, &sKl[ldso]);
            GLOAD16((const char*)vth_ + vb + (size_t)rloc * 2048 + chs, &sVh[ldso]);
            GLOAD16((const char*)vtl_ + vb + (size_t)rloc * 2048 + chs, &sVl[ldso]);
        }
        __syncthreads();

        // ---- S^T = K·Q^T
        f32x4 sacc[4];
#pragma unroll
        for (int s = 0; s < 4; ++s) {
            sacc[s] = (f32x4){0.f, 0.f, 0.f, 0.f};
            const int row = 16 * s + q;
#pragma unroll
            for (int k2 = 0; k2 < 2; ++k2) {
                const int ch = ((k2 * 4 + g) ^ (row & 7)) * 8;
                half8 kfh = *(const half8*)&sKh[row * 64 + ch];
                half8 kfl = *(const half8*)&sKl[row * 64 + ch];
                sacc[s] = MFMA16(kfh, Qh[k2], sacc[s]);
                sacc[s] = MFMA16(kfh, Ql[k2], sacc[s]);
                sacc[s] = MFMA16(kfl, Qh[k2], sacc[s]);
            }
        }

        // ---- relu + rowsum + split/pack
        uint32_t pkh[4][2], pkl[4][2];
#pragma unroll
        for (int s = 0; s < 4; ++s) {
            float p0 = fmaxf(sacc[s][0], 0.f), p1 = fmaxf(sacc[s][1], 0.f);
            float p2 = fmaxf(sacc[s][2], 0.f), p3 = fmaxf(sacc[s][3], 0.f);
            rs += (p0 + p1) + (p2 + p3);
            f16 h0, h1, h2, h3, l0, l1, l2, l3;
            split2(p0, h0, l0); split2(p1, h1, l1);
            split2(p2, h2, l2); split2(p3, h3, l3);
            pkh[s][0] = packh(h0, h1); pkh[s][1] = packh(h2, h3);
            pkl[s][0] = packh(l0, l1); pkl[s][1] = packh(l2, l3);
        }

        // ---- redistribute P via shfl butterfly, out^T += V^T·P
#pragma unroll
        for (int t2 = 0; t2 < 2; ++t2) {
            union { uint32_t u[4]; half8 v; } fh, fl;
#pragma unroll
            for (int r = 0; r < 4; ++r) {
                const int srcl = ((2 * g + (r >> 1)) & 3) * 16 + q;
                uint32_t a0 = __shfl(pkh[2 * t2][r & 1], srcl, 64);
                uint32_t b0 = __shfl(pkh[2 * t2 + 1][r & 1], srcl, 64);
                fh.u[r] = (g < 2) ? a0 : b0;
                uint32_t c0 = __shfl(pkl[2 * t2][r & 1], srcl, 64);
                uint32_t d0 = __shfl(pkl[2 * t2 + 1][r & 1], srcl, 64);
                fl.u[r] = (g < 2) ? c0 : d0;
            }
#pragma unroll
            for (int ds = 0; ds < 4; ++ds) {
                const int row = 16 * ds + q;
                const int ch = ((t2 * 4 + g) ^ (row & 7)) * 8;
                half8 vfh = *(const half8*)&sVh[row * 64 + ch];
                half8 vfl = *(const half8*)&sVl[row * 64 + ch];
                accP[ds] = MFMA16(vfh, fh.v, accP[ds]);
                accP[ds] = MFMA16(vfh, fl.v, accP[ds]);
                accP[ds] = MFMA16(vfl, fh.v, accP[ds]);
            }
        }

        if (useLin) {
            uint32_t skh[4][2], skl[4][2];
#pragma unroll
            for (int s = 0; s < 4; ++s) {
                f16 h0, h1, h2, h3, l0, l1, l2, l3;
                split2(sacc[s][0], h0, l0); split2(sacc[s][1], h1, l1);
                split2(sacc[s][2], h2, l2); split2(sacc[s][3], h3, l3);
                skh[s][0] = packh(h0, h1); skh[s][1] = packh(h2, h3);
                skl[s][0] = packh(l0, l1); skl[s][1] = packh(l2, l3);
            }
#pragma unroll
            for (int t2 = 0; t2 < 2; ++t2) {
                union { uint32_t u[4]; half8 v; } fh, fl;
#pragma unroll
                for (int r = 0; r < 4; ++r) {
                    const int srcl = ((2 * g + (r >> 1)) & 3) * 16 + q;
                    uint32_t a0 = __shfl(skh[2 * t2][r & 1], srcl, 64);
                    uint32_t b0 = __shfl(skh[2 * t2 + 1][r & 1], srcl, 64);
                    fh.u[r] = (g < 2) ? a0 : b0;
                    uint32_t c0 = __shfl(skl[2 * t2][r & 1], srcl, 64);
                    uint32_t d0 = __shfl(skl[2 * t2 + 1][r & 1], srcl, 64);
                    fl.u[r] = (g < 2) ? c0 : d0;
                }
#pragma unroll
                for (int ds = 0; ds < 4; ++ds) {
                    const int row = 16 * ds + q;
                    const int ch = ((t2 * 4 + g) ^ (row & 7)) * 8;
                    half8 vfh = *(const half8*)&sVh[row * 64 + ch];
                    half8 vfl = *(const half8*)&sVl[row * 64 + ch];
                    accS[ds] = MFMA16(vfh, fh.v, accS[ds]);
                    accS[ds] = MFMA16(vfh, fl.v, accS[ds]);
                    accS[ds] = MFMA16(vfl, fh.v, accS[ds]);
                }
            }
        }
        __syncthreads();
    }

    rs += __shfl_xor(rs, 16, 64);
    rs += __shfl_xor(rs, 32, 64);
    const float inv = al / (rs + 1e-5f);

    const int b = bh / 6;
    const size_t arow = (size_t)(b * 1024 + n0 + 16 * w + q) * 384 + h * 64;
#pragma unroll
    for (int ds = 0; ds < 4; ++ds) {
        const int d0 = 16 * ds + 4 * g;
        union { f16 x[4]; uint2 u; } H, L;
#pragma unroll
        for (int r = 0; r < 4; ++r) {
            float v = accP[ds][r] * inv + cg * accS[ds][r];
            split2(v, H.x[r], L.x[r]);
        }
        *(uint2*)&aoh[arow + d0] = H.u;
        *(uint2*)&aol[arow + d0] = L.u;
    }
}

// ---------------------------------------------------------------------------
// Kernel 3: out = aout @ Wproj^T + bias. Swapped operands -> float4 stores.
// grid (128, 3), block 256 (waves 2x2 of 32x64).
// ---------------------------------------------------------------------------
__global__ __launch_bounds__(256) void proj_gemm(
    const f16* __restrict__ ah_, const f16* __restrict__ al_,
    const f16* __restrict__ wh, const f16* __restrict__ wl,
    const float* __restrict__ bias, float* __restrict__ out) {
    __shared__ f16 sAh[64 * 32], sAl[64 * 32], sBh[128 * 32], sBl[128 * 32];
    const int tid = threadIdx.x;
    const int w = tid >> 6, lane = tid & 63;
    const int g = lane >> 4, q = lane & 15;
    const int m0 = blockIdx.x * 64, j0 = blockIdx.y * 128;
    const int wm = (w >> 1) * 32, wn = (w & 1) * 64;

    f32x4 acc[2][4];
#pragma unroll
    for (int i = 0; i < 2; ++i)
#pragma unroll
        for (int j = 0; j < 4; ++j) acc[i][j] = (f32x4){0.f, 0.f, 0.f, 0.f};

    for (int ks = 0; ks < 12; ++ks) {
        if (w < 2) {
            const char* gb = (const char*)(w == 0 ? ah_ : al_) + (size_t)m0 * 768 + ks * 64;
            f16* ld = (w == 0) ? sAh : sAl;
#pragma unroll
            for (int i = 0; i < 4; ++i) {
                const int row = i * 16 + (lane >> 2);
                GLOAD16(gb + (size_t)row * 768 + (((lane & 3) ^ ((row & 6) >> 1)) << 4),
                        ld + i * 512);
            }
        } else {
            const char* gb = (const char*)(w == 2 ? wh : wl) + (size_t)j0 * 768 + ks * 64;
            f16* ld = (w == 2) ? sBh : sBl;
#pragma unroll
            for (int i = 0; i < 8; ++i) {
                const int row = i * 16 + (lane >> 2);
                GLOAD16(gb + (size_t)row * 768 + (((lane & 3) ^ ((row & 6) >> 1)) << 4),
                        ld + i * 512);
            }
        }
        __syncthreads();

        half8 am_h[2], am_l[2], bn_h[4], bn_l[4];
#pragma unroll
        for (int mi = 0; mi < 2; ++mi) {
            const int row = wm + 16 * mi + q;
            const int ch = (g ^ ((row & 6) >> 1)) * 8;
            am_h[mi] = *(const half8*)&sAh[row * 32 + ch];
            am_l[mi] = *(const half8*)&sAl[row * 32 + ch];
        }
#pragma unroll
        for (int nj = 0; nj < 4; ++nj) {
            const int row = wn + 16 * nj + q;
            const int ch = (g ^ ((row & 6) >> 1)) * 8;
            bn_h[nj] = *(const half8*)&sBh[row * 32 + ch];
            bn_l[nj] = *(const half8*)&sBl[row * 32 + ch];
        }
#pragma unroll
        for (int mi = 0; mi < 2; ++mi)
#pragma unroll
            for (int nj = 0; nj < 4; ++nj) {
                // swapped: D rows(reg) = feature j, cols(lane&15) = m
                acc[mi][nj] = MFMA16(bn_h[nj], am_h[mi], acc[mi][nj]);
                acc[mi][nj] = MFMA16(bn_l[nj], am_h[mi], acc[mi][nj]);
                acc[mi][nj] = MFMA16(bn_h[nj], am_l[mi], acc[mi][nj]);
            }
        __syncthreads();
    }

#pragma unroll
    for (int nj = 0; nj < 4; ++nj) {
        const int jb = j0 + wn + 16 * nj + 4 * g;   // 4 consecutive features
        const float4 bb = *(const float4*)&bias[jb];
#pragma unroll
        for (int mi = 0; mi < 2; ++mi) {
            const int m = m0 + wm + 16 * mi + q;
            float4 o;
            o.x = acc[mi][nj][0] + bb.x;
            o.y = acc[mi][nj][1] + bb.y;
            o.z = acc[mi][nj][2] + bb.z;
            o.w = acc[mi][nj][3] + bb.w;
            *(float4*)&out[(size_t)m * 384 + jb] = o;
        }
    }
}

// ---------------------------------------------------------------------------
extern "C" void kernel_launch(void* const* d_in, const int* in_sizes, int n_in,
                              void* d_out, int out_size, void* d_ws, size_t ws_size,
                              hipStream_t stream) {
    const float* x     = (const float*)d_in[0];
    const float* Wqkv  = (const float*)d_in[1];
    const float* Wproj = (const float*)d_in[2];
    const float* bproj = (const float*)d_in[3];
    const float* alpha = (const float*)d_in[4];
    float* out = (float*)d_out;

    f16* ws = (f16*)d_ws;
    const size_t XE = 8192 * 384;
    const size_t WQ = 1152 * 384;
    const size_t WP = 384 * 384;
    const size_t QE = 48 * 1024 * 64;

    f16* xh  = ws;            f16* xl  = xh + XE;
    f16* wqh = xl + XE;       f16* wql = wqh + WQ;
    f16* wph = wql + WQ;      f16* wpl = wph + WP;
    f16* qh  = wpl + WP;      f16* ql  = qh + QE;
    f16* kh  = ql + QE;       f16* kl  = kh + QE;
    f16* vth = kl + QE;       f16* vtl = vth + QE;
    f16* aoh = vtl + QE;      f16* aol = aoh + XE;

    convert_all<<<1024, 256, 0, stream>>>(x, Wqkv, Wproj, xh, xl,
                                          wqh, wql, wph, wpl);
    // q/k tiles (j in [0,768)): swapped operands, vectorized [bh][n][d] stores
    qkv_gemm<true><<<dim3(64, 6), 256, 0, stream>>>(xh, xl, wqh, wql,
                                                    qh, ql, kh, kl, 0);
    // v tiles (j in [768,1152)): transposed [bh][d][n] stores
    qkv_gemm<false><<<dim3(64, 3), 256, 0, stream>>>(xh, xl, wqh, wql,
                                                     vth, vtl, nullptr, nullptr, 768);
    attn_mfma<<<768, 256, 0, stream>>>(qh, ql, kh, kl, vth, vtl,
                                       alpha, aoh, aol);
    proj_gemm<<<dim3(128, 3), 256, 0, stream>>>(aoh, aol, wph, wpl, bproj, out);
}